// Round 3
// baseline (632.864 us; speedup 1.0000x reference)
//
#include <hip/hip_runtime.h>

// APPNP-style propagation: 4 hops of M = 0.9*A_hat + 0.1*I on x[N,128], y[N,32].
// Round 10:
//  Hop fetch volume is at its compulsory floor (8 XCDs x 32MB working set
//  ~= 285 MB measured). Remaining gap is fetch-path *efficiency*
//  (2.8 TB/s observed). This round:
//   (a) zx/zy interleaved into one 320B per-node record (5 consecutive
//       lines): each edge's x+y payload is one contiguous burst.
//   (b) hop loop unrolled 2x: up to 10 independent gathers in flight per
//       wave (branch-guarded: deg<=16 rows issue only 5).
//   (c) detect fused into zero_kernel (one fewer launch).
//  passA (R8): WG-aggregated counting sort; passB unchanged.

#define NN 100000
#define EE 1600000
#define NPAD 100096     // N padded to multiple of 64
#define NBKT 391        // ceil(NN/256); bucket = src >> 8
#define CHUNK 4096      // edges per passA workgroup
#define CAP2 5120       // per-bucket capacity: mean 4092 + 16 sigma

#define GETREG_XCC_IMM (((32 - 1) << 11) | (0 << 6) | 20)   // HW_REG_XCC_ID, full width

// ---------- bf16 helpers (RNE) ----------
__device__ __forceinline__ float bflo(unsigned w) { return __uint_as_float(w << 16); }
__device__ __forceinline__ float bfhi(unsigned w) { return __uint_as_float(w & 0xffff0000u); }
__device__ __forceinline__ unsigned packbf(float a, float b) {
    unsigned ua = __float_as_uint(a), ub = __float_as_uint(b);
    unsigned ra = (ua + 0x7fffu + ((ua >> 16) & 1u)) >> 16;
    unsigned rb = (ub + 0x7fffu + ((ub >> 16) & 1u)) >> 16;
    return ra | (rb << 16);
}

// ---------- preprocessing ----------

// zero + int64/int32 edge-format detect fused
__global__ void zero_kernel(int* __restrict__ bufs, int total,
                            const int* __restrict__ raw, int* __restrict__ flag) {
    int i = blockIdx.x * blockDim.x + threadIdx.x;
    if (i < total) bufs[i] = 0;
    if (i == 0) {
        int is64 = 1;
        for (int k = 1; k < 16; k += 2) {
            if (raw[k] != 0) { is64 = 0; break; }
        }
        *flag = is64;
    }
}

// WG-aggregated bucket sort over a 4096-edge chunk.
__global__ __launch_bounds__(256) void passA_kernel(const void* __restrict__ raw,
                                                    const int* __restrict__ flag,
                                                    int* __restrict__ indeg_rep,
                                                    int* __restrict__ gbcur,
                                                    int* __restrict__ buf) {
    __shared__ unsigned short sh_b[CHUNK];      // bucket per original slot   (8 KB)
    __shared__ unsigned int   sh_p[CHUNK];      // packed (s&255)<<17 | d     (16 KB)
    __shared__ unsigned int   sh_sorted[CHUNK]; // bucket-ordered packed      (16 KB)
    __shared__ unsigned short sh_bs[CHUNK];     // bucket per sorted slot     (8 KB)
    __shared__ int hist[512];
    __shared__ int excl[512];
    __shared__ int gbase[512];
    __shared__ int lcur[512];                   // total 56 KB

    int tid = threadIdx.x;
    int base = blockIdx.x * CHUNK;
    int nval = EE - base; if (nval > CHUNK) nval = CHUNK;
    int r = __builtin_amdgcn_s_getreg(GETREG_XCC_IMM) & 7;   // wave-uniform XCD id
    int is64 = *flag;

    hist[tid] = 0; hist[tid + 256] = 0;
    __syncthreads();

    // load edges, indeg atomic (fire-and-forget), LDS bucket histogram
    for (int i = tid; i < nval; i += 256) {
        int e = base + i;
        int s, d;
        if (is64) {
            s = (int)((const long long*)raw)[e];
            d = (int)((const long long*)raw)[EE + e];
        } else {
            s = ((const int*)raw)[e];
            d = ((const int*)raw)[EE + e];
        }
        atomicAdd(&indeg_rep[r * NPAD + d], 1);
        int b = s >> 8;
        sh_b[i] = (unsigned short)b;
        sh_p[i] = ((unsigned)(s & 255) << 17) | (unsigned)d;
        atomicAdd(&hist[b], 1);
    }
    __syncthreads();

    // inclusive Hillis-Steele scan of hist (512 entries, 256 threads)
    excl[tid] = hist[tid];
    excl[tid + 256] = hist[tid + 256];
    __syncthreads();
    for (int off = 1; off < 512; off <<= 1) {
        int a0 = (tid >= off) ? excl[tid - off] : 0;
        int a1 = (tid + 256 >= off) ? excl[tid + 256 - off] : 0;
        __syncthreads();
        excl[tid] += a0;
        excl[tid + 256] += a1;
        __syncthreads();
    }
    // exclusive prefix + per-bucket global reservation
    int inc0 = excl[tid], inc1 = excl[tid + 256];
    int h0 = hist[tid],  h1 = hist[tid + 256];
    __syncthreads();
    int e0 = inc0 - h0, e1 = inc1 - h1;
    excl[tid] = e0; excl[tid + 256] = e1;
    lcur[tid] = e0; lcur[tid + 256] = e1;
    if (h0 > 0) gbase[tid]       = atomicAdd(&gbcur[tid * 16], h0);
    if (h1 > 0) gbase[tid + 256] = atomicAdd(&gbcur[(tid + 256) * 16], h1);
    __syncthreads();

    // LDS counting sort: place each edge into its bucket run
    for (int i = tid; i < nval; i += 256) {
        int b = sh_b[i];
        int pos = atomicAdd(&lcur[b], 1);
        sh_sorted[pos] = sh_p[i];
        sh_bs[pos] = (unsigned short)b;
    }
    __syncthreads();

    // stream out: consecutive sorted slots -> consecutive global addresses
    for (int i = tid; i < nval; i += 256) {
        int b = sh_bs[i];
        int gpos = gbase[b] + (i - excl[b]);
        if (gpos < CAP2)
            buf[(size_t)b * CAP2 + gpos] = (int)sh_sorted[i];
    }
}

// Exclusive prefix over bucket totals -> bucket_base; set rowptr[NN]=EE.
__global__ void bucket_scan_kernel(const int* __restrict__ gbcur, int* __restrict__ bucket_base,
                                   int* __restrict__ rowptr) {
    __shared__ int s[512];
    int tid = threadIdx.x;
    int v = 0;
    if (tid < NBKT) {
        int c = gbcur[tid * 16];
        v = (c < CAP2) ? c : CAP2;
    }
    s[tid] = v;
    __syncthreads();
    for (int off = 1; off < 512; off <<= 1) {
        int t = (tid >= off) ? s[tid - off] : 0;
        __syncthreads();
        s[tid] += t;
        __syncthreads();
    }
    if (tid < NBKT) bucket_base[tid] = s[tid] - v;
    if (tid == 0) rowptr[NN] = EE;
}

__global__ void dinv_kernel(const int* __restrict__ indeg_rep, float* __restrict__ dinv) {
    int i = blockIdx.x * blockDim.x + threadIdx.x;
    if (i < NN) {
        int ind = 1;
        #pragma unroll
        for (int r = 0; r < 8; ++r) ind += indeg_rep[r * NPAD + i];
        dinv[i] = rsqrtf((float)ind);
    }
}

// Cast fp32 inputs to pre-scaled bf16 interleaved record:
// zxy[node] = 20 x uint4 (320 B): [0..15] = x (128 bf16), [16..19] = y (32 bf16).
__global__ void cast_kernel(const float4* __restrict__ x0, const float4* __restrict__ y0,
                            const float* __restrict__ dinv, uint4* __restrict__ zxy) {
    int t = blockIdx.x * blockDim.x + threadIdx.x;
    if (t < NN * 16) {
        int node = t >> 4, c = t & 15;
        float di = dinv[node];
        float4 a = x0[(size_t)node * 32 + c * 2];
        float4 b = x0[(size_t)node * 32 + c * 2 + 1];
        uint4 o;
        o.x = packbf(di * a.x, di * a.y); o.y = packbf(di * a.z, di * a.w);
        o.z = packbf(di * b.x, di * b.y); o.w = packbf(di * b.z, di * b.w);
        zxy[(size_t)node * 20 + c] = o;
    } else if (t < NN * 20) {
        int u = t - NN * 16;
        int node = u >> 2, c = u & 3;
        float di = dinv[node];
        float4 a = y0[(size_t)node * 8 + c * 2];
        float4 b = y0[(size_t)node * 8 + c * 2 + 1];
        uint4 o;
        o.x = packbf(di * a.x, di * a.y); o.y = packbf(di * a.z, di * a.w);
        o.z = packbf(di * b.x, di * b.y); o.w = packbf(di * b.z, di * b.w);
        zxy[(size_t)node * 20 + 16 + c] = o;
    }
}

// One WG per bucket: stage run + histogram -> scan -> rowptr + contiguous dst slice.
__global__ __launch_bounds__(256) void passB_kernel(const int* __restrict__ gbcur,
                                                    const int* __restrict__ buf,
                                                    const int* __restrict__ bucket_base,
                                                    int* __restrict__ rowptr,
                                                    int* __restrict__ dst_sorted) {
    int b = blockIdx.x;
    int tid = threadIdx.x;
    __shared__ int edges[CAP2];      // 20 KB
    __shared__ int hist[256];
    __shared__ int sc[256];
    __shared__ int base_s, tot_s;

    if (tid == 0) {
        int c = gbcur[b * 16];
        tot_s = (c < CAP2) ? c : CAP2;
        base_s = bucket_base[b];
    }
    hist[tid] = 0;
    __syncthreads();
    int total = tot_s;
    const int* src = buf + (size_t)b * CAP2;
    for (int i = tid; i < total; i += 256) {
        int p = src[i];
        edges[i] = p;
        atomicAdd(&hist[p >> 17], 1);
    }
    __syncthreads();
    int hv = hist[tid];
    sc[tid] = hv;
    __syncthreads();
    for (int o = 1; o < 256; o <<= 1) {
        int t = (tid >= o) ? sc[tid - o] : 0;
        __syncthreads();
        sc[tid] += t;
        __syncthreads();
    }
    int excl = sc[tid] - hv;
    int node = (b << 8) + tid;
    if (node < NN) rowptr[node] = base_s + excl;
    hist[tid] = excl;
    __syncthreads();
    for (int i = tid; i < total; i += 256) {
        int p = edges[i];
        int pos = atomicAdd(&hist[p >> 17], 1);
        dst_sorted[base_s + pos] = p & 0x1ffff;
    }
}

// ---------- fused per-hop kernel ----------
// Iterates stored pre-scaled z = dinv*u (bf16), interleaved 320B/node records.
// Per row: u'_row = 0.9*di*sum_e z[d_e] + (0.9*di + 0.1/di)*z_row;
//          store z' = di*u' (or u' fp32 on final hop).
// Loop: 32-edge iterations, up to 10 independent 16B gathers in flight.
template <bool OUTBF>
__global__ __launch_bounds__(256) void hop_kernel(const int* __restrict__ rowptr,
                                                  const int* __restrict__ dst_sorted,
                                                  const float* __restrict__ dinv,
                                                  const uint4* __restrict__ z,
                                                  void* __restrict__ nx,
                                                  void* __restrict__ ny) {
    int t = blockIdx.x * blockDim.x + threadIdx.x;
    int row = t >> 6, lane = t & 63;
    if (row >= NN) return;
    int beg = rowptr[row], end = rowptr[row + 1];
    float di = dinv[row];

    int g = lane >> 4, sub = lane & 15;    // x: 4 edge-groups x 16 lanes
    int gy = lane >> 2, sy = lane & 3;     // y: 16 edge-groups x 4 lanes

    float ax[8] = {0.f, 0.f, 0.f, 0.f, 0.f, 0.f, 0.f, 0.f};
    float ay[8] = {0.f, 0.f, 0.f, 0.f, 0.f, 0.f, 0.f, 0.f};

    int last = (end > beg) ? end - 1 : beg;   // deg==0-safe clamp target

    for (int e0 = beg; e0 < end; e0 += 32) {
        // ---- batch A: edges e0 .. e0+15 ----
        int a0 = e0 + g, a1 = e0 + 4 + g, a2 = e0 + 8 + g, a3 = e0 + 12 + g;
        int aY = e0 + gy;
        int dA0 = dst_sorted[min(a0, last)];
        int dA1 = dst_sorted[min(a1, last)];
        int dA2 = dst_sorted[min(a2, last)];
        int dA3 = dst_sorted[min(a3, last)];
        int dAy = dst_sorted[min(aY, last)];
        uint4 wA0 = z[(size_t)dA0 * 20 + sub];
        uint4 wA1 = z[(size_t)dA1 * 20 + sub];
        uint4 wA2 = z[(size_t)dA2 * 20 + sub];
        uint4 wA3 = z[(size_t)dA3 * 20 + sub];
        uint4 wAy = z[(size_t)dAy * 20 + 16 + sy];
        float mA0 = (a0 <= last) ? 1.f : 0.f;
        float mA1 = (a1 <= last) ? 1.f : 0.f;
        float mA2 = (a2 <= last) ? 1.f : 0.f;
        float mA3 = (a3 <= last) ? 1.f : 0.f;
        float mAy = (aY <= last) ? 1.f : 0.f;

        bool doB = (e0 + 16) < end;     // wave-uniform
        if (doB) {
            // ---- batch B: edges e0+16 .. e0+31, issued before A's accumulate ----
            int b0 = e0 + 16 + g, b1 = e0 + 20 + g, b2 = e0 + 24 + g, b3 = e0 + 28 + g;
            int bY = e0 + 16 + gy;
            int dB0 = dst_sorted[min(b0, last)];
            int dB1 = dst_sorted[min(b1, last)];
            int dB2 = dst_sorted[min(b2, last)];
            int dB3 = dst_sorted[min(b3, last)];
            int dBy = dst_sorted[min(bY, last)];
            uint4 wB0 = z[(size_t)dB0 * 20 + sub];
            uint4 wB1 = z[(size_t)dB1 * 20 + sub];
            uint4 wB2 = z[(size_t)dB2 * 20 + sub];
            uint4 wB3 = z[(size_t)dB3 * 20 + sub];
            uint4 wBy = z[(size_t)dBy * 20 + 16 + sy];
            float mB0 = (b0 <= last) ? 1.f : 0.f;
            float mB1 = (b1 <= last) ? 1.f : 0.f;
            float mB2 = (b2 <= last) ? 1.f : 0.f;
            float mB3 = (b3 <= last) ? 1.f : 0.f;
            float mBy = (bY <= last) ? 1.f : 0.f;

            ax[0] += mA0 * bflo(wA0.x); ax[1] += mA0 * bfhi(wA0.x);
            ax[2] += mA0 * bflo(wA0.y); ax[3] += mA0 * bfhi(wA0.y);
            ax[4] += mA0 * bflo(wA0.z); ax[5] += mA0 * bfhi(wA0.z);
            ax[6] += mA0 * bflo(wA0.w); ax[7] += mA0 * bfhi(wA0.w);
            ax[0] += mA1 * bflo(wA1.x); ax[1] += mA1 * bfhi(wA1.x);
            ax[2] += mA1 * bflo(wA1.y); ax[3] += mA1 * bfhi(wA1.y);
            ax[4] += mA1 * bflo(wA1.z); ax[5] += mA1 * bfhi(wA1.z);
            ax[6] += mA1 * bflo(wA1.w); ax[7] += mA1 * bfhi(wA1.w);
            ax[0] += mA2 * bflo(wA2.x); ax[1] += mA2 * bfhi(wA2.x);
            ax[2] += mA2 * bflo(wA2.y); ax[3] += mA2 * bfhi(wA2.y);
            ax[4] += mA2 * bflo(wA2.z); ax[5] += mA2 * bfhi(wA2.z);
            ax[6] += mA2 * bflo(wA2.w); ax[7] += mA2 * bfhi(wA2.w);
            ax[0] += mA3 * bflo(wA3.x); ax[1] += mA3 * bfhi(wA3.x);
            ax[2] += mA3 * bflo(wA3.y); ax[3] += mA3 * bfhi(wA3.y);
            ax[4] += mA3 * bflo(wA3.z); ax[5] += mA3 * bfhi(wA3.z);
            ax[6] += mA3 * bflo(wA3.w); ax[7] += mA3 * bfhi(wA3.w);
            ay[0] += mAy * bflo(wAy.x); ay[1] += mAy * bfhi(wAy.x);
            ay[2] += mAy * bflo(wAy.y); ay[3] += mAy * bfhi(wAy.y);
            ay[4] += mAy * bflo(wAy.z); ay[5] += mAy * bfhi(wAy.z);
            ay[6] += mAy * bflo(wAy.w); ay[7] += mAy * bfhi(wAy.w);

            ax[0] += mB0 * bflo(wB0.x); ax[1] += mB0 * bfhi(wB0.x);
            ax[2] += mB0 * bflo(wB0.y); ax[3] += mB0 * bfhi(wB0.y);
            ax[4] += mB0 * bflo(wB0.z); ax[5] += mB0 * bfhi(wB0.z);
            ax[6] += mB0 * bflo(wB0.w); ax[7] += mB0 * bfhi(wB0.w);
            ax[0] += mB1 * bflo(wB1.x); ax[1] += mB1 * bfhi(wB1.x);
            ax[2] += mB1 * bflo(wB1.y); ax[3] += mB1 * bfhi(wB1.y);
            ax[4] += mB1 * bflo(wB1.z); ax[5] += mB1 * bfhi(wB1.z);
            ax[6] += mB1 * bflo(wB1.w); ax[7] += mB1 * bfhi(wB1.w);
            ax[0] += mB2 * bflo(wB2.x); ax[1] += mB2 * bfhi(wB2.x);
            ax[2] += mB2 * bflo(wB2.y); ax[3] += mB2 * bfhi(wB2.y);
            ax[4] += mB2 * bflo(wB2.z); ax[5] += mB2 * bfhi(wB2.z);
            ax[6] += mB2 * bflo(wB2.w); ax[7] += mB2 * bfhi(wB2.w);
            ax[0] += mB3 * bflo(wB3.x); ax[1] += mB3 * bfhi(wB3.x);
            ax[2] += mB3 * bflo(wB3.y); ax[3] += mB3 * bfhi(wB3.y);
            ax[4] += mB3 * bflo(wB3.z); ax[5] += mB3 * bfhi(wB3.z);
            ax[6] += mB3 * bflo(wB3.w); ax[7] += mB3 * bfhi(wB3.w);
            ay[0] += mBy * bflo(wBy.x); ay[1] += mBy * bfhi(wBy.x);
            ay[2] += mBy * bflo(wBy.y); ay[3] += mBy * bfhi(wBy.y);
            ay[4] += mBy * bflo(wBy.z); ay[5] += mBy * bfhi(wBy.z);
            ay[6] += mBy * bflo(wBy.w); ay[7] += mBy * bfhi(wBy.w);
        } else {
            ax[0] += mA0 * bflo(wA0.x); ax[1] += mA0 * bfhi(wA0.x);
            ax[2] += mA0 * bflo(wA0.y); ax[3] += mA0 * bfhi(wA0.y);
            ax[4] += mA0 * bflo(wA0.z); ax[5] += mA0 * bfhi(wA0.z);
            ax[6] += mA0 * bflo(wA0.w); ax[7] += mA0 * bfhi(wA0.w);
            ax[0] += mA1 * bflo(wA1.x); ax[1] += mA1 * bfhi(wA1.x);
            ax[2] += mA1 * bflo(wA1.y); ax[3] += mA1 * bfhi(wA1.y);
            ax[4] += mA1 * bflo(wA1.z); ax[5] += mA1 * bfhi(wA1.z);
            ax[6] += mA1 * bflo(wA1.w); ax[7] += mA1 * bfhi(wA1.w);
            ax[0] += mA2 * bflo(wA2.x); ax[1] += mA2 * bfhi(wA2.x);
            ax[2] += mA2 * bflo(wA2.y); ax[3] += mA2 * bfhi(wA2.y);
            ax[4] += mA2 * bflo(wA2.z); ax[5] += mA2 * bfhi(wA2.z);
            ax[6] += mA2 * bflo(wA2.w); ax[7] += mA2 * bfhi(wA2.w);
            ax[0] += mA3 * bflo(wA3.x); ax[1] += mA3 * bfhi(wA3.x);
            ax[2] += mA3 * bflo(wA3.y); ax[3] += mA3 * bfhi(wA3.y);
            ax[4] += mA3 * bflo(wA3.z); ax[5] += mA3 * bfhi(wA3.z);
            ax[6] += mA3 * bflo(wA3.w); ax[7] += mA3 * bfhi(wA3.w);
            ay[0] += mAy * bflo(wAy.x); ay[1] += mAy * bfhi(wAy.x);
            ay[2] += mAy * bflo(wAy.y); ay[3] += mAy * bfhi(wAy.y);
            ay[4] += mAy * bflo(wAy.z); ay[5] += mAy * bfhi(wAy.z);
            ay[6] += mAy * bflo(wAy.w); ay[7] += mAy * bfhi(wAy.w);
        }
    }

    #pragma unroll
    for (int m = 16; m <= 32; m <<= 1) {
        #pragma unroll
        for (int i = 0; i < 8; ++i) ax[i] += __shfl_xor(ax[i], m);
    }
    #pragma unroll
    for (int m = 4; m <= 32; m <<= 1) {
        #pragma unroll
        for (int i = 0; i < 8; ++i) ay[i] += __shfl_xor(ay[i], m);
    }

    float sg = 0.9f * di;
    float sl = 0.9f * di + 0.1f / di;   // coefficient on z_row giving the u-space self term

    if (g == 0) {   // lanes 0..15 write x
        uint4 wz = z[(size_t)row * 20 + sub];
        float c[8] = { bflo(wz.x), bfhi(wz.x), bflo(wz.y), bfhi(wz.y),
                       bflo(wz.z), bfhi(wz.z), bflo(wz.w), bfhi(wz.w) };
        float r[8];
        #pragma unroll
        for (int i = 0; i < 8; ++i) r[i] = sg * ax[i] + sl * c[i];   // u'
        if constexpr (OUTBF) {
            uint4 o;
            o.x = packbf(di * r[0], di * r[1]); o.y = packbf(di * r[2], di * r[3]);
            o.z = packbf(di * r[4], di * r[5]); o.w = packbf(di * r[6], di * r[7]);
            ((uint4*)nx)[(size_t)row * 20 + sub] = o;
        } else {
            float4 a, b;
            a.x = r[0]; a.y = r[1]; a.z = r[2]; a.w = r[3];
            b.x = r[4]; b.y = r[5]; b.z = r[6]; b.w = r[7];
            ((float4*)nx)[(size_t)row * 32 + sub * 2]     = a;
            ((float4*)nx)[(size_t)row * 32 + sub * 2 + 1] = b;
        }
    }
    if (gy == 0) {  // lanes 0..3 write y
        uint4 wz = z[(size_t)row * 20 + 16 + sy];
        float c[8] = { bflo(wz.x), bfhi(wz.x), bflo(wz.y), bfhi(wz.y),
                       bflo(wz.z), bfhi(wz.z), bflo(wz.w), bfhi(wz.w) };
        float r[8];
        #pragma unroll
        for (int i = 0; i < 8; ++i) r[i] = sg * ay[i] + sl * c[i];
        if constexpr (OUTBF) {
            uint4 o;
            o.x = packbf(di * r[0], di * r[1]); o.y = packbf(di * r[2], di * r[3]);
            o.z = packbf(di * r[4], di * r[5]); o.w = packbf(di * r[6], di * r[7]);
            ((uint4*)nx)[(size_t)row * 20 + 16 + sy] = o;
        } else {
            float4 a, b;
            a.x = r[0]; a.y = r[1]; a.z = r[2]; a.w = r[3];
            b.x = r[4]; b.y = r[5]; b.z = r[6]; b.w = r[7];
            ((float4*)ny)[(size_t)row * 8 + sy * 2]     = a;
            ((float4*)ny)[(size_t)row * 8 + sy * 2 + 1] = b;
        }
    }
}

extern "C" void kernel_launch(void* const* d_in, const int* in_sizes, int n_in,
                              void* d_out, int out_size, void* d_ws, size_t ws_size,
                              hipStream_t stream) {
    const float* x0  = (const float*)d_in[0];
    const float* y0  = (const float*)d_in[1];
    const void*  raw = d_in[2];

    float* out_x = (float*)d_out;
    float* out_y = out_x + (size_t)NN * 128;

    // ws layout (4-byte words):
    // flag[16] | indeg_rep[8*NPAD] | gbcur[512*16] | bucket_base[512] | rowptr[100112]
    // | dinv[NPAD] | buf[NBKT*CAP2] | dst_sorted[EE] | zxyA[N*80] | zxyB[N*80]  ~= 78 MB
    int*   flag        = (int*)d_ws;
    int*   indeg_rep   = flag + 16;
    int*   gbcur       = indeg_rep + 8 * NPAD;
    int*   bucket_base = gbcur + 512 * 16;
    int*   rowptr      = bucket_base + 512;
    float* dinv        = (float*)(rowptr + 100112);
    int*   buf         = (int*)(dinv + NPAD);
    int*   dst_sorted  = buf + (size_t)NBKT * CAP2;
    uint4* zxyA        = (uint4*)(dst_sorted + EE);
    uint4* zxyB        = zxyA + (size_t)NN * 20;

    const int B = 256;
    const int GW = (NN * 64 + B - 1) / B;   // one wave per row
    const int ZTOT = 8 * NPAD + 512 * 16;

    zero_kernel<<<(ZTOT + B - 1) / B, B, 0, stream>>>(indeg_rep, ZTOT, (const int*)raw, flag);
    passA_kernel<<<(EE + CHUNK - 1) / CHUNK, 256, 0, stream>>>(raw, flag, indeg_rep, gbcur, buf);
    bucket_scan_kernel<<<1, 512, 0, stream>>>(gbcur, bucket_base, rowptr);
    dinv_kernel<<<(NN + B - 1) / B, B, 0, stream>>>(indeg_rep, dinv);
    cast_kernel<<<(NN * 20 + B - 1) / B, B, 0, stream>>>(
        (const float4*)x0, (const float4*)y0, dinv, zxyA);
    passB_kernel<<<NBKT, 256, 0, stream>>>(gbcur, buf, bucket_base, rowptr, dst_sorted);

    // hops 1-3: bf16 z -> bf16 z ; hop 4: bf16 z -> fp32 u (d_out)
    hop_kernel<true><<<GW, B, 0, stream>>>(rowptr, dst_sorted, dinv, zxyA, zxyB, zxyB);
    hop_kernel<true><<<GW, B, 0, stream>>>(rowptr, dst_sorted, dinv, zxyB, zxyA, zxyA);
    hop_kernel<true><<<GW, B, 0, stream>>>(rowptr, dst_sorted, dinv, zxyA, zxyB, zxyB);
    hop_kernel<false><<<GW, B, 0, stream>>>(rowptr, dst_sorted, dinv, zxyB, out_x, out_y);
}

// Round 4
// 607.039 us; speedup vs baseline: 1.0425x; 1.0425x over previous
//
#include <hip/hip_runtime.h>

// APPNP-style propagation: 4 hops of M = 0.9*A_hat + 0.1*I on x[N,128], y[N,32].
// Round 11:
//  - hop_kernel REVERTED to R9 structure (verified 101.8us/hop): split zx/zy,
//    single 16-edge batch, 5 independent gathers in flight. R10's 2x unroll +
//    320B interleave halved occupancy and regressed; fetch path is saturated
//    at ~2.8 TB/s for this random-gather pattern (more MLP does not help).
//  - passA: CHUNK 4096->2048, LDS 56KB->~32KB => 2 WGs/CU -> 5 WGs/CU.
//    passA is latency-heavy (edge loads + 3.2M LDS atomics + scans); 2.5x
//    more resident waves should ~halve its time.
//  - zero+detect stay fused.

#define NN 100000
#define EE 1600000
#define NPAD 100096     // N padded to multiple of 64
#define NBKT 391        // ceil(NN/256); bucket = src >> 8
#define CHUNK 2048      // edges per passA workgroup (R11: was 4096)
#define CAP2 5120       // per-bucket capacity: mean 4092 + 16 sigma

#define GETREG_XCC_IMM (((32 - 1) << 11) | (0 << 6) | 20)   // HW_REG_XCC_ID, full width

// ---------- bf16 helpers (RNE) ----------
__device__ __forceinline__ float bflo(unsigned w) { return __uint_as_float(w << 16); }
__device__ __forceinline__ float bfhi(unsigned w) { return __uint_as_float(w & 0xffff0000u); }
__device__ __forceinline__ unsigned packbf(float a, float b) {
    unsigned ua = __float_as_uint(a), ub = __float_as_uint(b);
    unsigned ra = (ua + 0x7fffu + ((ua >> 16) & 1u)) >> 16;
    unsigned rb = (ub + 0x7fffu + ((ub >> 16) & 1u)) >> 16;
    return ra | (rb << 16);
}

// ---------- preprocessing ----------

// zero + int64/int32 edge-format detect fused
__global__ void zero_kernel(int* __restrict__ bufs, int total,
                            const int* __restrict__ raw, int* __restrict__ flag) {
    int i = blockIdx.x * blockDim.x + threadIdx.x;
    if (i < total) bufs[i] = 0;
    if (i == 0) {
        int is64 = 1;
        for (int k = 1; k < 16; k += 2) {
            if (raw[k] != 0) { is64 = 0; break; }
        }
        *flag = is64;
    }
}

// WG-aggregated bucket sort over a 2048-edge chunk.
__global__ __launch_bounds__(256) void passA_kernel(const void* __restrict__ raw,
                                                    const int* __restrict__ flag,
                                                    int* __restrict__ indeg_rep,
                                                    int* __restrict__ gbcur,
                                                    int* __restrict__ buf) {
    __shared__ unsigned short sh_b[CHUNK];      // bucket per original slot   (4 KB)
    __shared__ unsigned int   sh_p[CHUNK];      // packed (s&255)<<17 | d     (8 KB)
    __shared__ unsigned int   sh_sorted[CHUNK]; // bucket-ordered packed      (8 KB)
    __shared__ unsigned short sh_bs[CHUNK];     // bucket per sorted slot     (4 KB)
    __shared__ int hist[512];
    __shared__ int excl[512];
    __shared__ int gbase[512];
    __shared__ int lcur[512];                   // 8 KB; total ~32 KB

    int tid = threadIdx.x;
    int base = blockIdx.x * CHUNK;
    int nval = EE - base; if (nval > CHUNK) nval = CHUNK;
    int r = __builtin_amdgcn_s_getreg(GETREG_XCC_IMM) & 7;   // wave-uniform XCD id
    int is64 = *flag;

    hist[tid] = 0; hist[tid + 256] = 0;
    __syncthreads();

    // load edges, indeg atomic (fire-and-forget), LDS bucket histogram
    for (int i = tid; i < nval; i += 256) {
        int e = base + i;
        int s, d;
        if (is64) {
            s = (int)((const long long*)raw)[e];
            d = (int)((const long long*)raw)[EE + e];
        } else {
            s = ((const int*)raw)[e];
            d = ((const int*)raw)[EE + e];
        }
        atomicAdd(&indeg_rep[r * NPAD + d], 1);
        int b = s >> 8;
        sh_b[i] = (unsigned short)b;
        sh_p[i] = ((unsigned)(s & 255) << 17) | (unsigned)d;
        atomicAdd(&hist[b], 1);
    }
    __syncthreads();

    // inclusive Hillis-Steele scan of hist (512 entries, 256 threads)
    excl[tid] = hist[tid];
    excl[tid + 256] = hist[tid + 256];
    __syncthreads();
    for (int off = 1; off < 512; off <<= 1) {
        int a0 = (tid >= off) ? excl[tid - off] : 0;
        int a1 = (tid + 256 >= off) ? excl[tid + 256 - off] : 0;
        __syncthreads();
        excl[tid] += a0;
        excl[tid + 256] += a1;
        __syncthreads();
    }
    // exclusive prefix + per-bucket global reservation
    int inc0 = excl[tid], inc1 = excl[tid + 256];
    int h0 = hist[tid],  h1 = hist[tid + 256];
    __syncthreads();
    int e0 = inc0 - h0, e1 = inc1 - h1;
    excl[tid] = e0; excl[tid + 256] = e1;
    lcur[tid] = e0; lcur[tid + 256] = e1;
    if (h0 > 0) gbase[tid]       = atomicAdd(&gbcur[tid * 16], h0);
    if (h1 > 0) gbase[tid + 256] = atomicAdd(&gbcur[(tid + 256) * 16], h1);
    __syncthreads();

    // LDS counting sort: place each edge into its bucket run
    for (int i = tid; i < nval; i += 256) {
        int b = sh_b[i];
        int pos = atomicAdd(&lcur[b], 1);
        sh_sorted[pos] = sh_p[i];
        sh_bs[pos] = (unsigned short)b;
    }
    __syncthreads();

    // stream out: consecutive sorted slots -> consecutive global addresses
    for (int i = tid; i < nval; i += 256) {
        int b = sh_bs[i];
        int gpos = gbase[b] + (i - excl[b]);
        if (gpos < CAP2)
            buf[(size_t)b * CAP2 + gpos] = (int)sh_sorted[i];
    }
}

// Exclusive prefix over bucket totals -> bucket_base; set rowptr[NN]=EE.
__global__ void bucket_scan_kernel(const int* __restrict__ gbcur, int* __restrict__ bucket_base,
                                   int* __restrict__ rowptr) {
    __shared__ int s[512];
    int tid = threadIdx.x;
    int v = 0;
    if (tid < NBKT) {
        int c = gbcur[tid * 16];
        v = (c < CAP2) ? c : CAP2;
    }
    s[tid] = v;
    __syncthreads();
    for (int off = 1; off < 512; off <<= 1) {
        int t = (tid >= off) ? s[tid - off] : 0;
        __syncthreads();
        s[tid] += t;
        __syncthreads();
    }
    if (tid < NBKT) bucket_base[tid] = s[tid] - v;
    if (tid == 0) rowptr[NN] = EE;
}

__global__ void dinv_kernel(const int* __restrict__ indeg_rep, float* __restrict__ dinv) {
    int i = blockIdx.x * blockDim.x + threadIdx.x;
    if (i < NN) {
        int ind = 1;
        #pragma unroll
        for (int r = 0; r < 8; ++r) ind += indeg_rep[r * NPAD + i];
        dinv[i] = rsqrtf((float)ind);
    }
}

// Cast fp32 inputs to pre-scaled bf16: zx[i] = dinv[i]*x0[i], zy[i] = dinv[i]*y0[i].
__global__ void cast_kernel(const float4* __restrict__ x0, const float4* __restrict__ y0,
                            const float* __restrict__ dinv, uint4* __restrict__ zx,
                            uint4* __restrict__ zy) {
    int t = blockIdx.x * blockDim.x + threadIdx.x;
    if (t < NN * 16) {
        int node = t >> 4, c = t & 15;
        float di = dinv[node];
        float4 a = x0[(size_t)node * 32 + c * 2];
        float4 b = x0[(size_t)node * 32 + c * 2 + 1];
        uint4 o;
        o.x = packbf(di * a.x, di * a.y); o.y = packbf(di * a.z, di * a.w);
        o.z = packbf(di * b.x, di * b.y); o.w = packbf(di * b.z, di * b.w);
        zx[(size_t)node * 16 + c] = o;
    } else if (t < NN * 20) {
        int u = t - NN * 16;
        int node = u >> 2, c = u & 3;
        float di = dinv[node];
        float4 a = y0[(size_t)node * 8 + c * 2];
        float4 b = y0[(size_t)node * 8 + c * 2 + 1];
        uint4 o;
        o.x = packbf(di * a.x, di * a.y); o.y = packbf(di * a.z, di * a.w);
        o.z = packbf(di * b.x, di * b.y); o.w = packbf(di * b.z, di * b.w);
        zy[(size_t)node * 4 + c] = o;
    }
}

// One WG per bucket: stage run + histogram -> scan -> rowptr + contiguous dst slice.
__global__ __launch_bounds__(256) void passB_kernel(const int* __restrict__ gbcur,
                                                    const int* __restrict__ buf,
                                                    const int* __restrict__ bucket_base,
                                                    int* __restrict__ rowptr,
                                                    int* __restrict__ dst_sorted) {
    int b = blockIdx.x;
    int tid = threadIdx.x;
    __shared__ int edges[CAP2];      // 20 KB
    __shared__ int hist[256];
    __shared__ int sc[256];
    __shared__ int base_s, tot_s;

    if (tid == 0) {
        int c = gbcur[b * 16];
        tot_s = (c < CAP2) ? c : CAP2;
        base_s = bucket_base[b];
    }
    hist[tid] = 0;
    __syncthreads();
    int total = tot_s;
    const int* src = buf + (size_t)b * CAP2;
    for (int i = tid; i < total; i += 256) {
        int p = src[i];
        edges[i] = p;
        atomicAdd(&hist[p >> 17], 1);
    }
    __syncthreads();
    int hv = hist[tid];
    sc[tid] = hv;
    __syncthreads();
    for (int o = 1; o < 256; o <<= 1) {
        int t = (tid >= o) ? sc[tid - o] : 0;
        __syncthreads();
        sc[tid] += t;
        __syncthreads();
    }
    int excl = sc[tid] - hv;
    int node = (b << 8) + tid;
    if (node < NN) rowptr[node] = base_s + excl;
    hist[tid] = excl;
    __syncthreads();
    for (int i = tid; i < total; i += 256) {
        int p = edges[i];
        int pos = atomicAdd(&hist[p >> 17], 1);
        dst_sorted[base_s + pos] = p & 0x1ffff;
    }
}

// ---------- fused per-hop kernel (R9 structure) ----------
// Iterates stored pre-scaled: z = dinv*u (bf16). Per row:
//   u'_row = 0.9*di*sum_e z[d_e] + (0.9*di + 0.1/di)*z_row ; store z' = di*u' (or u' fp32).
// Merged 16-edge-batch loop: 5 independent gathers per iteration (MLP=5).
template <bool OUTBF>
__global__ __launch_bounds__(256) void hop_kernel(const int* __restrict__ rowptr,
                                                  const int* __restrict__ dst_sorted,
                                                  const float* __restrict__ dinv,
                                                  const uint4* __restrict__ zx,
                                                  const uint4* __restrict__ zy,
                                                  void* __restrict__ nx,
                                                  void* __restrict__ ny) {
    int t = blockIdx.x * blockDim.x + threadIdx.x;
    int row = t >> 6, lane = t & 63;
    if (row >= NN) return;
    int beg = rowptr[row], end = rowptr[row + 1];
    float di = dinv[row];

    int g = lane >> 4, sub = lane & 15;    // x: 4 edge-groups x 16 lanes
    int gy = lane >> 2, sy = lane & 3;     // y: 16 edge-groups x 4 lanes

    float ax[8] = {0.f, 0.f, 0.f, 0.f, 0.f, 0.f, 0.f, 0.f};
    float ay[8] = {0.f, 0.f, 0.f, 0.f, 0.f, 0.f, 0.f, 0.f};

    int last = (end > beg) ? end - 1 : beg;
    for (int e0 = beg; e0 < end; e0 += 16) {
        int ex0 = e0 + g, ex1 = e0 + 4 + g, ex2 = e0 + 8 + g, ex3 = e0 + 12 + g;
        int ey = e0 + gy;
        // clamped indices -> always-valid addresses; contribution masked by 0/1
        int d0 = dst_sorted[min(ex0, last)];
        int d1 = dst_sorted[min(ex1, last)];
        int d2 = dst_sorted[min(ex2, last)];
        int d3 = dst_sorted[min(ex3, last)];
        int dy = dst_sorted[min(ey, last)];
        // 5 independent 16B gathers, all in flight together
        uint4 w0 = zx[(size_t)d0 * 16 + sub];
        uint4 w1 = zx[(size_t)d1 * 16 + sub];
        uint4 w2 = zx[(size_t)d2 * 16 + sub];
        uint4 w3 = zx[(size_t)d3 * 16 + sub];
        uint4 wy = zy[(size_t)dy * 4 + sy];
        float m0 = (ex0 <= last) ? 1.f : 0.f;
        float m1 = (ex1 <= last) ? 1.f : 0.f;
        float m2 = (ex2 <= last) ? 1.f : 0.f;
        float m3 = (ex3 <= last) ? 1.f : 0.f;
        float my = (ey  <= last) ? 1.f : 0.f;

        ax[0] += m0 * bflo(w0.x); ax[1] += m0 * bfhi(w0.x);
        ax[2] += m0 * bflo(w0.y); ax[3] += m0 * bfhi(w0.y);
        ax[4] += m0 * bflo(w0.z); ax[5] += m0 * bfhi(w0.z);
        ax[6] += m0 * bflo(w0.w); ax[7] += m0 * bfhi(w0.w);

        ax[0] += m1 * bflo(w1.x); ax[1] += m1 * bfhi(w1.x);
        ax[2] += m1 * bflo(w1.y); ax[3] += m1 * bfhi(w1.y);
        ax[4] += m1 * bflo(w1.z); ax[5] += m1 * bfhi(w1.z);
        ax[6] += m1 * bflo(w1.w); ax[7] += m1 * bfhi(w1.w);

        ax[0] += m2 * bflo(w2.x); ax[1] += m2 * bfhi(w2.x);
        ax[2] += m2 * bflo(w2.y); ax[3] += m2 * bfhi(w2.y);
        ax[4] += m2 * bflo(w2.z); ax[5] += m2 * bfhi(w2.z);
        ax[6] += m2 * bflo(w2.w); ax[7] += m2 * bfhi(w2.w);

        ax[0] += m3 * bflo(w3.x); ax[1] += m3 * bfhi(w3.x);
        ax[2] += m3 * bflo(w3.y); ax[3] += m3 * bfhi(w3.y);
        ax[4] += m3 * bflo(w3.z); ax[5] += m3 * bfhi(w3.z);
        ax[6] += m3 * bflo(w3.w); ax[7] += m3 * bfhi(w3.w);

        ay[0] += my * bflo(wy.x); ay[1] += my * bfhi(wy.x);
        ay[2] += my * bflo(wy.y); ay[3] += my * bfhi(wy.y);
        ay[4] += my * bflo(wy.z); ay[5] += my * bfhi(wy.z);
        ay[6] += my * bflo(wy.w); ay[7] += my * bfhi(wy.w);
    }

    #pragma unroll
    for (int m = 16; m <= 32; m <<= 1) {
        #pragma unroll
        for (int i = 0; i < 8; ++i) ax[i] += __shfl_xor(ax[i], m);
    }
    #pragma unroll
    for (int m = 4; m <= 32; m <<= 1) {
        #pragma unroll
        for (int i = 0; i < 8; ++i) ay[i] += __shfl_xor(ay[i], m);
    }

    float sg = 0.9f * di;
    float sl = 0.9f * di + 0.1f / di;   // coefficient on z_row giving the u-space self term

    if (g == 0) {   // lanes 0..15 write x
        uint4 wz = zx[(size_t)row * 16 + sub];
        float c[8] = { bflo(wz.x), bfhi(wz.x), bflo(wz.y), bfhi(wz.y),
                       bflo(wz.z), bfhi(wz.z), bflo(wz.w), bfhi(wz.w) };
        float r[8];
        #pragma unroll
        for (int i = 0; i < 8; ++i) r[i] = sg * ax[i] + sl * c[i];   // u'
        if constexpr (OUTBF) {
            uint4 o;
            o.x = packbf(di * r[0], di * r[1]); o.y = packbf(di * r[2], di * r[3]);
            o.z = packbf(di * r[4], di * r[5]); o.w = packbf(di * r[6], di * r[7]);
            ((uint4*)nx)[(size_t)row * 16 + sub] = o;
        } else {
            float4 a, b;
            a.x = r[0]; a.y = r[1]; a.z = r[2]; a.w = r[3];
            b.x = r[4]; b.y = r[5]; b.z = r[6]; b.w = r[7];
            ((float4*)nx)[(size_t)row * 32 + sub * 2]     = a;
            ((float4*)nx)[(size_t)row * 32 + sub * 2 + 1] = b;
        }
    }
    if (gy == 0) {  // lanes 0..3 write y
        uint4 wz = zy[(size_t)row * 4 + sy];
        float c[8] = { bflo(wz.x), bfhi(wz.x), bflo(wz.y), bfhi(wz.y),
                       bflo(wz.z), bfhi(wz.z), bflo(wz.w), bfhi(wz.w) };
        float r[8];
        #pragma unroll
        for (int i = 0; i < 8; ++i) r[i] = sg * ay[i] + sl * c[i];
        if constexpr (OUTBF) {
            uint4 o;
            o.x = packbf(di * r[0], di * r[1]); o.y = packbf(di * r[2], di * r[3]);
            o.z = packbf(di * r[4], di * r[5]); o.w = packbf(di * r[6], di * r[7]);
            ((uint4*)ny)[(size_t)row * 4 + sy] = o;
        } else {
            float4 a, b;
            a.x = r[0]; a.y = r[1]; a.z = r[2]; a.w = r[3];
            b.x = r[4]; b.y = r[5]; b.z = r[6]; b.w = r[7];
            ((float4*)ny)[(size_t)row * 8 + sy * 2]     = a;
            ((float4*)ny)[(size_t)row * 8 + sy * 2 + 1] = b;
        }
    }
}

extern "C" void kernel_launch(void* const* d_in, const int* in_sizes, int n_in,
                              void* d_out, int out_size, void* d_ws, size_t ws_size,
                              hipStream_t stream) {
    const float* x0  = (const float*)d_in[0];
    const float* y0  = (const float*)d_in[1];
    const void*  raw = d_in[2];

    float* out_x = (float*)d_out;
    float* out_y = out_x + (size_t)NN * 128;

    // ws layout (4-byte words):
    // flag[16] | indeg_rep[8*NPAD] | gbcur[512*16] | bucket_base[512] | rowptr[100112]
    // | dinv[NPAD] | buf[NBKT*CAP2] | dst_sorted[EE] | zxA[N*64] | zxB[N*64]
    // | zyA[N*16] | zyB[N*16]   ~= 78 MB
    int*   flag        = (int*)d_ws;
    int*   indeg_rep   = flag + 16;
    int*   gbcur       = indeg_rep + 8 * NPAD;
    int*   bucket_base = gbcur + 512 * 16;
    int*   rowptr      = bucket_base + 512;
    float* dinv        = (float*)(rowptr + 100112);
    int*   buf         = (int*)(dinv + NPAD);
    int*   dst_sorted  = buf + (size_t)NBKT * CAP2;
    uint4* zxA         = (uint4*)(dst_sorted + EE);
    uint4* zxB         = zxA + (size_t)NN * 16;
    uint4* zyA         = (uint4*)(zxB + (size_t)NN * 16);
    uint4* zyB         = zyA + (size_t)NN * 4;

    const int B = 256;
    const int GW = (NN * 64 + B - 1) / B;   // one wave per row
    const int ZTOT = 8 * NPAD + 512 * 16;

    zero_kernel<<<(ZTOT + B - 1) / B, B, 0, stream>>>(indeg_rep, ZTOT, (const int*)raw, flag);
    passA_kernel<<<(EE + CHUNK - 1) / CHUNK, 256, 0, stream>>>(raw, flag, indeg_rep, gbcur, buf);
    bucket_scan_kernel<<<1, 512, 0, stream>>>(gbcur, bucket_base, rowptr);
    dinv_kernel<<<(NN + B - 1) / B, B, 0, stream>>>(indeg_rep, dinv);
    cast_kernel<<<(NN * 20 + B - 1) / B, B, 0, stream>>>(
        (const float4*)x0, (const float4*)y0, dinv, zxA, zyA);
    passB_kernel<<<NBKT, 256, 0, stream>>>(gbcur, buf, bucket_base, rowptr, dst_sorted);

    // hops 1-3: bf16 z -> bf16 z ; hop 4: bf16 z -> fp32 u (d_out)
    hop_kernel<true><<<GW, B, 0, stream>>>(rowptr, dst_sorted, dinv, zxA, zyA, zxB, zyB);
    hop_kernel<true><<<GW, B, 0, stream>>>(rowptr, dst_sorted, dinv, zxB, zyB, zxA, zyA);
    hop_kernel<true><<<GW, B, 0, stream>>>(rowptr, dst_sorted, dinv, zxA, zyA, zxB, zyB);
    hop_kernel<false><<<GW, B, 0, stream>>>(rowptr, dst_sorted, dinv, zxB, zyB, out_x, out_y);
}

// Round 6
// 602.021 us; speedup vs baseline: 1.0512x; 1.0083x over previous
//
#include <hip/hip_runtime.h>

// APPNP-style propagation: 4 hops of M = 0.9*A_hat + 0.1*I on x[N,128], y[N,32].
// Round 13 (= R12 with compile fix):
//  - __builtin_nontemporal_store requires clang-native ext_vector types, not
//    HIP_vector_type uint4/float4 -> nt stores routed through uintv4/floatv4.
//  - passA CHUNK 4096 (R11's 2048 regressed: per-WG scan cost is CHUNK-indep).
//  - hop_kernel: R9 structure + NT stores for z / final outputs (bf16 hops
//    showed WRITE_SIZE 62.5MB vs 32MB payload -> 2x write amplification;
//    z is written once, re-read only after full 32MB cycle >> 4MB L2).
//  - cast_kernel also uses nt stores.

#define NN 100000
#define EE 1600000
#define NPAD 100096     // N padded to multiple of 64
#define NBKT 391        // ceil(NN/256); bucket = src >> 8
#define CHUNK 4096      // edges per passA workgroup
#define CAP2 5120       // per-bucket capacity: mean 4092 + 16 sigma

#define GETREG_XCC_IMM (((32 - 1) << 11) | (0 << 6) | 20)   // HW_REG_XCC_ID, full width

// clang-native 4-wide vectors for nontemporal builtins
typedef unsigned int uintv4 __attribute__((ext_vector_type(4)));
typedef float floatv4 __attribute__((ext_vector_type(4)));

__device__ __forceinline__ void nt_store_u4(uint4 v, uint4* p) {
    uintv4 w; w.x = v.x; w.y = v.y; w.z = v.z; w.w = v.w;
    __builtin_nontemporal_store(w, (uintv4*)p);
}
__device__ __forceinline__ void nt_store_f4(float4 v, float4* p) {
    floatv4 w; w.x = v.x; w.y = v.y; w.z = v.z; w.w = v.w;
    __builtin_nontemporal_store(w, (floatv4*)p);
}

// ---------- bf16 helpers (RNE) ----------
__device__ __forceinline__ float bflo(unsigned w) { return __uint_as_float(w << 16); }
__device__ __forceinline__ float bfhi(unsigned w) { return __uint_as_float(w & 0xffff0000u); }
__device__ __forceinline__ unsigned packbf(float a, float b) {
    unsigned ua = __float_as_uint(a), ub = __float_as_uint(b);
    unsigned ra = (ua + 0x7fffu + ((ua >> 16) & 1u)) >> 16;
    unsigned rb = (ub + 0x7fffu + ((ub >> 16) & 1u)) >> 16;
    return ra | (rb << 16);
}

// ---------- preprocessing ----------

// zero + int64/int32 edge-format detect fused
__global__ void zero_kernel(int* __restrict__ bufs, int total,
                            const int* __restrict__ raw, int* __restrict__ flag) {
    int i = blockIdx.x * blockDim.x + threadIdx.x;
    if (i < total) bufs[i] = 0;
    if (i == 0) {
        int is64 = 1;
        for (int k = 1; k < 16; k += 2) {
            if (raw[k] != 0) { is64 = 0; break; }
        }
        *flag = is64;
    }
}

// WG-aggregated bucket sort over a 4096-edge chunk.
__global__ __launch_bounds__(256) void passA_kernel(const void* __restrict__ raw,
                                                    const int* __restrict__ flag,
                                                    int* __restrict__ indeg_rep,
                                                    int* __restrict__ gbcur,
                                                    int* __restrict__ buf) {
    __shared__ unsigned short sh_b[CHUNK];      // bucket per original slot   (8 KB)
    __shared__ unsigned int   sh_p[CHUNK];      // packed (s&255)<<17 | d     (16 KB)
    __shared__ unsigned int   sh_sorted[CHUNK]; // bucket-ordered packed      (16 KB)
    __shared__ unsigned short sh_bs[CHUNK];     // bucket per sorted slot     (8 KB)
    __shared__ int hist[512];
    __shared__ int excl[512];
    __shared__ int gbase[512];
    __shared__ int lcur[512];                   // total 56 KB

    int tid = threadIdx.x;
    int base = blockIdx.x * CHUNK;
    int nval = EE - base; if (nval > CHUNK) nval = CHUNK;
    int r = __builtin_amdgcn_s_getreg(GETREG_XCC_IMM) & 7;   // wave-uniform XCD id
    int is64 = *flag;

    hist[tid] = 0; hist[tid + 256] = 0;
    __syncthreads();

    // load edges, indeg atomic (fire-and-forget), LDS bucket histogram
    for (int i = tid; i < nval; i += 256) {
        int e = base + i;
        int s, d;
        if (is64) {
            s = (int)((const long long*)raw)[e];
            d = (int)((const long long*)raw)[EE + e];
        } else {
            s = ((const int*)raw)[e];
            d = ((const int*)raw)[EE + e];
        }
        atomicAdd(&indeg_rep[r * NPAD + d], 1);
        int b = s >> 8;
        sh_b[i] = (unsigned short)b;
        sh_p[i] = ((unsigned)(s & 255) << 17) | (unsigned)d;
        atomicAdd(&hist[b], 1);
    }
    __syncthreads();

    // inclusive Hillis-Steele scan of hist (512 entries, 256 threads)
    excl[tid] = hist[tid];
    excl[tid + 256] = hist[tid + 256];
    __syncthreads();
    for (int off = 1; off < 512; off <<= 1) {
        int a0 = (tid >= off) ? excl[tid - off] : 0;
        int a1 = (tid + 256 >= off) ? excl[tid + 256 - off] : 0;
        __syncthreads();
        excl[tid] += a0;
        excl[tid + 256] += a1;
        __syncthreads();
    }
    // exclusive prefix + per-bucket global reservation
    int inc0 = excl[tid], inc1 = excl[tid + 256];
    int h0 = hist[tid],  h1 = hist[tid + 256];
    __syncthreads();
    int e0 = inc0 - h0, e1 = inc1 - h1;
    excl[tid] = e0; excl[tid + 256] = e1;
    lcur[tid] = e0; lcur[tid + 256] = e1;
    if (h0 > 0) gbase[tid]       = atomicAdd(&gbcur[tid * 16], h0);
    if (h1 > 0) gbase[tid + 256] = atomicAdd(&gbcur[(tid + 256) * 16], h1);
    __syncthreads();

    // LDS counting sort: place each edge into its bucket run
    for (int i = tid; i < nval; i += 256) {
        int b = sh_b[i];
        int pos = atomicAdd(&lcur[b], 1);
        sh_sorted[pos] = sh_p[i];
        sh_bs[pos] = (unsigned short)b;
    }
    __syncthreads();

    // stream out: consecutive sorted slots -> consecutive global addresses
    for (int i = tid; i < nval; i += 256) {
        int b = sh_bs[i];
        int gpos = gbase[b] + (i - excl[b]);
        if (gpos < CAP2)
            buf[(size_t)b * CAP2 + gpos] = (int)sh_sorted[i];
    }
}

// Exclusive prefix over bucket totals -> bucket_base; set rowptr[NN]=EE.
__global__ void bucket_scan_kernel(const int* __restrict__ gbcur, int* __restrict__ bucket_base,
                                   int* __restrict__ rowptr) {
    __shared__ int s[512];
    int tid = threadIdx.x;
    int v = 0;
    if (tid < NBKT) {
        int c = gbcur[tid * 16];
        v = (c < CAP2) ? c : CAP2;
    }
    s[tid] = v;
    __syncthreads();
    for (int off = 1; off < 512; off <<= 1) {
        int t = (tid >= off) ? s[tid - off] : 0;
        __syncthreads();
        s[tid] += t;
        __syncthreads();
    }
    if (tid < NBKT) bucket_base[tid] = s[tid] - v;
    if (tid == 0) rowptr[NN] = EE;
}

__global__ void dinv_kernel(const int* __restrict__ indeg_rep, float* __restrict__ dinv) {
    int i = blockIdx.x * blockDim.x + threadIdx.x;
    if (i < NN) {
        int ind = 1;
        #pragma unroll
        for (int r = 0; r < 8; ++r) ind += indeg_rep[r * NPAD + i];
        dinv[i] = rsqrtf((float)ind);
    }
}

// Cast fp32 inputs to pre-scaled bf16: zx[i] = dinv[i]*x0[i], zy[i] = dinv[i]*y0[i].
__global__ void cast_kernel(const float4* __restrict__ x0, const float4* __restrict__ y0,
                            const float* __restrict__ dinv, uint4* __restrict__ zx,
                            uint4* __restrict__ zy) {
    int t = blockIdx.x * blockDim.x + threadIdx.x;
    if (t < NN * 16) {
        int node = t >> 4, c = t & 15;
        float di = dinv[node];
        float4 a = x0[(size_t)node * 32 + c * 2];
        float4 b = x0[(size_t)node * 32 + c * 2 + 1];
        uint4 o;
        o.x = packbf(di * a.x, di * a.y); o.y = packbf(di * a.z, di * a.w);
        o.z = packbf(di * b.x, di * b.y); o.w = packbf(di * b.z, di * b.w);
        nt_store_u4(o, &zx[(size_t)node * 16 + c]);
    } else if (t < NN * 20) {
        int u = t - NN * 16;
        int node = u >> 2, c = u & 3;
        float di = dinv[node];
        float4 a = y0[(size_t)node * 8 + c * 2];
        float4 b = y0[(size_t)node * 8 + c * 2 + 1];
        uint4 o;
        o.x = packbf(di * a.x, di * a.y); o.y = packbf(di * a.z, di * a.w);
        o.z = packbf(di * b.x, di * b.y); o.w = packbf(di * b.z, di * b.w);
        nt_store_u4(o, &zy[(size_t)node * 4 + c]);
    }
}

// One WG per bucket: stage run + histogram -> scan -> rowptr + contiguous dst slice.
__global__ __launch_bounds__(256) void passB_kernel(const int* __restrict__ gbcur,
                                                    const int* __restrict__ buf,
                                                    const int* __restrict__ bucket_base,
                                                    int* __restrict__ rowptr,
                                                    int* __restrict__ dst_sorted) {
    int b = blockIdx.x;
    int tid = threadIdx.x;
    __shared__ int edges[CAP2];      // 20 KB
    __shared__ int hist[256];
    __shared__ int sc[256];
    __shared__ int base_s, tot_s;

    if (tid == 0) {
        int c = gbcur[b * 16];
        tot_s = (c < CAP2) ? c : CAP2;
        base_s = bucket_base[b];
    }
    hist[tid] = 0;
    __syncthreads();
    int total = tot_s;
    const int* src = buf + (size_t)b * CAP2;
    for (int i = tid; i < total; i += 256) {
        int p = src[i];
        edges[i] = p;
        atomicAdd(&hist[p >> 17], 1);
    }
    __syncthreads();
    int hv = hist[tid];
    sc[tid] = hv;
    __syncthreads();
    for (int o = 1; o < 256; o <<= 1) {
        int t = (tid >= o) ? sc[tid - o] : 0;
        __syncthreads();
        sc[tid] += t;
        __syncthreads();
    }
    int excl = sc[tid] - hv;
    int node = (b << 8) + tid;
    if (node < NN) rowptr[node] = base_s + excl;
    hist[tid] = excl;
    __syncthreads();
    for (int i = tid; i < total; i += 256) {
        int p = edges[i];
        int pos = atomicAdd(&hist[p >> 17], 1);
        dst_sorted[base_s + pos] = p & 0x1ffff;
    }
}

// ---------- fused per-hop kernel (R9 structure + nt stores) ----------
// Iterates stored pre-scaled: z = dinv*u (bf16). Per row:
//   u'_row = 0.9*di*sum_e z[d_e] + (0.9*di + 0.1/di)*z_row ; store z' = di*u' (or u' fp32).
// Merged 16-edge-batch loop: 5 independent gathers per iteration (MLP=5).
template <bool OUTBF>
__global__ __launch_bounds__(256) void hop_kernel(const int* __restrict__ rowptr,
                                                  const int* __restrict__ dst_sorted,
                                                  const float* __restrict__ dinv,
                                                  const uint4* __restrict__ zx,
                                                  const uint4* __restrict__ zy,
                                                  void* __restrict__ nx,
                                                  void* __restrict__ ny) {
    int t = blockIdx.x * blockDim.x + threadIdx.x;
    int row = t >> 6, lane = t & 63;
    if (row >= NN) return;
    int beg = rowptr[row], end = rowptr[row + 1];
    float di = dinv[row];

    int g = lane >> 4, sub = lane & 15;    // x: 4 edge-groups x 16 lanes
    int gy = lane >> 2, sy = lane & 3;     // y: 16 edge-groups x 4 lanes

    float ax[8] = {0.f, 0.f, 0.f, 0.f, 0.f, 0.f, 0.f, 0.f};
    float ay[8] = {0.f, 0.f, 0.f, 0.f, 0.f, 0.f, 0.f, 0.f};

    int last = (end > beg) ? end - 1 : beg;
    for (int e0 = beg; e0 < end; e0 += 16) {
        int ex0 = e0 + g, ex1 = e0 + 4 + g, ex2 = e0 + 8 + g, ex3 = e0 + 12 + g;
        int ey = e0 + gy;
        // clamped indices -> always-valid addresses; contribution masked by 0/1
        int d0 = dst_sorted[min(ex0, last)];
        int d1 = dst_sorted[min(ex1, last)];
        int d2 = dst_sorted[min(ex2, last)];
        int d3 = dst_sorted[min(ex3, last)];
        int dy = dst_sorted[min(ey, last)];
        // 5 independent 16B gathers, all in flight together
        uint4 w0 = zx[(size_t)d0 * 16 + sub];
        uint4 w1 = zx[(size_t)d1 * 16 + sub];
        uint4 w2 = zx[(size_t)d2 * 16 + sub];
        uint4 w3 = zx[(size_t)d3 * 16 + sub];
        uint4 wy = zy[(size_t)dy * 4 + sy];
        float m0 = (ex0 <= last) ? 1.f : 0.f;
        float m1 = (ex1 <= last) ? 1.f : 0.f;
        float m2 = (ex2 <= last) ? 1.f : 0.f;
        float m3 = (ex3 <= last) ? 1.f : 0.f;
        float my = (ey  <= last) ? 1.f : 0.f;

        ax[0] += m0 * bflo(w0.x); ax[1] += m0 * bfhi(w0.x);
        ax[2] += m0 * bflo(w0.y); ax[3] += m0 * bfhi(w0.y);
        ax[4] += m0 * bflo(w0.z); ax[5] += m0 * bfhi(w0.z);
        ax[6] += m0 * bflo(w0.w); ax[7] += m0 * bfhi(w0.w);

        ax[0] += m1 * bflo(w1.x); ax[1] += m1 * bfhi(w1.x);
        ax[2] += m1 * bflo(w1.y); ax[3] += m1 * bfhi(w1.y);
        ax[4] += m1 * bflo(w1.z); ax[5] += m1 * bfhi(w1.z);
        ax[6] += m1 * bflo(w1.w); ax[7] += m1 * bfhi(w1.w);

        ax[0] += m2 * bflo(w2.x); ax[1] += m2 * bfhi(w2.x);
        ax[2] += m2 * bflo(w2.y); ax[3] += m2 * bfhi(w2.y);
        ax[4] += m2 * bflo(w2.z); ax[5] += m2 * bfhi(w2.z);
        ax[6] += m2 * bflo(w2.w); ax[7] += m2 * bfhi(w2.w);

        ax[0] += m3 * bflo(w3.x); ax[1] += m3 * bfhi(w3.x);
        ax[2] += m3 * bflo(w3.y); ax[3] += m3 * bfhi(w3.y);
        ax[4] += m3 * bflo(w3.z); ax[5] += m3 * bfhi(w3.z);
        ax[6] += m3 * bflo(w3.w); ax[7] += m3 * bfhi(w3.w);

        ay[0] += my * bflo(wy.x); ay[1] += my * bfhi(wy.x);
        ay[2] += my * bflo(wy.y); ay[3] += my * bfhi(wy.y);
        ay[4] += my * bflo(wy.z); ay[5] += my * bfhi(wy.z);
        ay[6] += my * bflo(wy.w); ay[7] += my * bfhi(wy.w);
    }

    #pragma unroll
    for (int m = 16; m <= 32; m <<= 1) {
        #pragma unroll
        for (int i = 0; i < 8; ++i) ax[i] += __shfl_xor(ax[i], m);
    }
    #pragma unroll
    for (int m = 4; m <= 32; m <<= 1) {
        #pragma unroll
        for (int i = 0; i < 8; ++i) ay[i] += __shfl_xor(ay[i], m);
    }

    float sg = 0.9f * di;
    float sl = 0.9f * di + 0.1f / di;   // coefficient on z_row giving the u-space self term

    if (g == 0) {   // lanes 0..15 write x
        uint4 wz = zx[(size_t)row * 16 + sub];
        float c[8] = { bflo(wz.x), bfhi(wz.x), bflo(wz.y), bfhi(wz.y),
                       bflo(wz.z), bfhi(wz.z), bflo(wz.w), bfhi(wz.w) };
        float r[8];
        #pragma unroll
        for (int i = 0; i < 8; ++i) r[i] = sg * ax[i] + sl * c[i];   // u'
        if constexpr (OUTBF) {
            uint4 o;
            o.x = packbf(di * r[0], di * r[1]); o.y = packbf(di * r[2], di * r[3]);
            o.z = packbf(di * r[4], di * r[5]); o.w = packbf(di * r[6], di * r[7]);
            nt_store_u4(o, &((uint4*)nx)[(size_t)row * 16 + sub]);
        } else {
            float4 a, b;
            a.x = r[0]; a.y = r[1]; a.z = r[2]; a.w = r[3];
            b.x = r[4]; b.y = r[5]; b.z = r[6]; b.w = r[7];
            nt_store_f4(a, &((float4*)nx)[(size_t)row * 32 + sub * 2]);
            nt_store_f4(b, &((float4*)nx)[(size_t)row * 32 + sub * 2 + 1]);
        }
    }
    if (gy == 0) {  // lanes 0..3 write y
        uint4 wz = zy[(size_t)row * 4 + sy];
        float c[8] = { bflo(wz.x), bfhi(wz.x), bflo(wz.y), bfhi(wz.y),
                       bflo(wz.z), bfhi(wz.z), bflo(wz.w), bfhi(wz.w) };
        float r[8];
        #pragma unroll
        for (int i = 0; i < 8; ++i) r[i] = sg * ay[i] + sl * c[i];
        if constexpr (OUTBF) {
            uint4 o;
            o.x = packbf(di * r[0], di * r[1]); o.y = packbf(di * r[2], di * r[3]);
            o.z = packbf(di * r[4], di * r[5]); o.w = packbf(di * r[6], di * r[7]);
            nt_store_u4(o, &((uint4*)ny)[(size_t)row * 4 + sy]);
        } else {
            float4 a, b;
            a.x = r[0]; a.y = r[1]; a.z = r[2]; a.w = r[3];
            b.x = r[4]; b.y = r[5]; b.z = r[6]; b.w = r[7];
            nt_store_f4(a, &((float4*)ny)[(size_t)row * 8 + sy * 2]);
            nt_store_f4(b, &((float4*)ny)[(size_t)row * 8 + sy * 2 + 1]);
        }
    }
}

extern "C" void kernel_launch(void* const* d_in, const int* in_sizes, int n_in,
                              void* d_out, int out_size, void* d_ws, size_t ws_size,
                              hipStream_t stream) {
    const float* x0  = (const float*)d_in[0];
    const float* y0  = (const float*)d_in[1];
    const void*  raw = d_in[2];

    float* out_x = (float*)d_out;
    float* out_y = out_x + (size_t)NN * 128;

    // ws layout (4-byte words):
    // flag[16] | indeg_rep[8*NPAD] | gbcur[512*16] | bucket_base[512] | rowptr[100112]
    // | dinv[NPAD] | buf[NBKT*CAP2] | dst_sorted[EE] | zxA[N*64] | zxB[N*64]
    // | zyA[N*16] | zyB[N*16]   ~= 78 MB
    int*   flag        = (int*)d_ws;
    int*   indeg_rep   = flag + 16;
    int*   gbcur       = indeg_rep + 8 * NPAD;
    int*   bucket_base = gbcur + 512 * 16;
    int*   rowptr      = bucket_base + 512;
    float* dinv        = (float*)(rowptr + 100112);
    int*   buf         = (int*)(dinv + NPAD);
    int*   dst_sorted  = buf + (size_t)NBKT * CAP2;
    uint4* zxA         = (uint4*)(dst_sorted + EE);
    uint4* zxB         = zxA + (size_t)NN * 16;
    uint4* zyA         = (uint4*)(zxB + (size_t)NN * 16);
    uint4* zyB         = zyA + (size_t)NN * 4;

    const int B = 256;
    const int GW = (NN * 64 + B - 1) / B;   // one wave per row
    const int ZTOT = 8 * NPAD + 512 * 16;

    zero_kernel<<<(ZTOT + B - 1) / B, B, 0, stream>>>(indeg_rep, ZTOT, (const int*)raw, flag);
    passA_kernel<<<(EE + CHUNK - 1) / CHUNK, 256, 0, stream>>>(raw, flag, indeg_rep, gbcur, buf);
    bucket_scan_kernel<<<1, 512, 0, stream>>>(gbcur, bucket_base, rowptr);
    dinv_kernel<<<(NN + B - 1) / B, B, 0, stream>>>(indeg_rep, dinv);
    cast_kernel<<<(NN * 20 + B - 1) / B, B, 0, stream>>>(
        (const float4*)x0, (const float4*)y0, dinv, zxA, zyA);
    passB_kernel<<<NBKT, 256, 0, stream>>>(gbcur, buf, bucket_base, rowptr, dst_sorted);

    // hops 1-3: bf16 z -> bf16 z ; hop 4: bf16 z -> fp32 u (d_out)
    hop_kernel<true><<<GW, B, 0, stream>>>(rowptr, dst_sorted, dinv, zxA, zyA, zxB, zyB);
    hop_kernel<true><<<GW, B, 0, stream>>>(rowptr, dst_sorted, dinv, zxB, zyB, zxA, zyA);
    hop_kernel<true><<<GW, B, 0, stream>>>(rowptr, dst_sorted, dinv, zxA, zyA, zxB, zyB);
    hop_kernel<false><<<GW, B, 0, stream>>>(rowptr, dst_sorted, dinv, zxB, zyB, out_x, out_y);
}

// Round 8
// 587.400 us; speedup vs baseline: 1.0774x; 1.0249x over previous
//
#include <hip/hip_runtime.h>
#include <hip/hip_fp16.h>

// APPNP-style propagation: 4 hops of M = 0.9*A_hat + 0.1*I on x[N,128], y[N,32].
// Round 15 (= R14 resubmitted; previous bench died on container infra, not code):
//  - nt stores REVERTED (R13: WRITE_SIZE halved as predicted but hops got
//    2.8% slower -> writes were never on the critical path; nt write-through
//    contends with the read stream).
//  - z format bf16 -> f16: enables v_fma_mix_f32 (fma directly from packed
//    f16 halves, no separate unpack op) cutting inner-loop VALU ~35%
//    (VALUBusy was 61-64% -> co-limiting), and epilogue pack becomes one
//    v_cvt_pkrtz per pair instead of ~6-op manual bf16 RNE. f16 also has
//    3 more mantissa bits than bf16 -> absmax improves.
//  - hop structure = R9/R11 (verified best: 16-edge batch, 5 gathers in
//    flight); fetch path saturated at ~2.8 TB/s for this pattern, volume at
//    the 8-XCD compulsory floor (~285 MB) -> only VALU + write side movable.
//  - passA CHUNK=4096 (R11's 2048 regressed: scan cost is CHUNK-independent).

#define NN 100000
#define EE 1600000
#define NPAD 100096     // N padded to multiple of 64
#define NBKT 391        // ceil(NN/256); bucket = src >> 8
#define CHUNK 4096      // edges per passA workgroup
#define CAP2 5120       // per-bucket capacity: mean 4092 + 16 sigma

#define GETREG_XCC_IMM (((32 - 1) << 11) | (0 << 6) | 20)   // HW_REG_XCC_ID, full width

// ---------- f16 helpers ----------
__device__ __forceinline__ unsigned packh(float a, float b) {
    __half2 h = __floats2half2_rn(a, b);
    return *reinterpret_cast<unsigned*>(&h);
}
// accumulate 8 packed f16 (uint4) into a[0..7] with scalar mask m (fma_mix path)
__device__ __forceinline__ void acc8(float* a, uint4 w, float m) {
    const __half2* h = reinterpret_cast<const __half2*>(&w);
    #pragma unroll
    for (int i = 0; i < 4; ++i) {
        a[2 * i]     = fmaf(m, __half2float(__low2half(h[i])),  a[2 * i]);
        a[2 * i + 1] = fmaf(m, __half2float(__high2half(h[i])), a[2 * i + 1]);
    }
}
// unpack 8 packed f16 (uint4) into c[0..7]
__device__ __forceinline__ void unp8(float* c, uint4 w) {
    const __half2* h = reinterpret_cast<const __half2*>(&w);
    #pragma unroll
    for (int i = 0; i < 4; ++i) {
        float2 f = __half22float2(h[i]);
        c[2 * i] = f.x; c[2 * i + 1] = f.y;
    }
}

// ---------- preprocessing ----------

// zero + int64/int32 edge-format detect fused
__global__ void zero_kernel(int* __restrict__ bufs, int total,
                            const int* __restrict__ raw, int* __restrict__ flag) {
    int i = blockIdx.x * blockDim.x + threadIdx.x;
    if (i < total) bufs[i] = 0;
    if (i == 0) {
        int is64 = 1;
        for (int k = 1; k < 16; k += 2) {
            if (raw[k] != 0) { is64 = 0; break; }
        }
        *flag = is64;
    }
}

// WG-aggregated bucket sort over a 4096-edge chunk.
__global__ __launch_bounds__(256) void passA_kernel(const void* __restrict__ raw,
                                                    const int* __restrict__ flag,
                                                    int* __restrict__ indeg_rep,
                                                    int* __restrict__ gbcur,
                                                    int* __restrict__ buf) {
    __shared__ unsigned short sh_b[CHUNK];      // bucket per original slot   (8 KB)
    __shared__ unsigned int   sh_p[CHUNK];      // packed (s&255)<<17 | d     (16 KB)
    __shared__ unsigned int   sh_sorted[CHUNK]; // bucket-ordered packed      (16 KB)
    __shared__ unsigned short sh_bs[CHUNK];     // bucket per sorted slot     (8 KB)
    __shared__ int hist[512];
    __shared__ int excl[512];
    __shared__ int gbase[512];
    __shared__ int lcur[512];                   // total 56 KB

    int tid = threadIdx.x;
    int base = blockIdx.x * CHUNK;
    int nval = EE - base; if (nval > CHUNK) nval = CHUNK;
    int r = __builtin_amdgcn_s_getreg(GETREG_XCC_IMM) & 7;   // wave-uniform XCD id
    int is64 = *flag;

    hist[tid] = 0; hist[tid + 256] = 0;
    __syncthreads();

    // load edges, indeg atomic (fire-and-forget), LDS bucket histogram
    for (int i = tid; i < nval; i += 256) {
        int e = base + i;
        int s, d;
        if (is64) {
            s = (int)((const long long*)raw)[e];
            d = (int)((const long long*)raw)[EE + e];
        } else {
            s = ((const int*)raw)[e];
            d = ((const int*)raw)[EE + e];
        }
        atomicAdd(&indeg_rep[r * NPAD + d], 1);
        int b = s >> 8;
        sh_b[i] = (unsigned short)b;
        sh_p[i] = ((unsigned)(s & 255) << 17) | (unsigned)d;
        atomicAdd(&hist[b], 1);
    }
    __syncthreads();

    // inclusive Hillis-Steele scan of hist (512 entries, 256 threads)
    excl[tid] = hist[tid];
    excl[tid + 256] = hist[tid + 256];
    __syncthreads();
    for (int off = 1; off < 512; off <<= 1) {
        int a0 = (tid >= off) ? excl[tid - off] : 0;
        int a1 = (tid + 256 >= off) ? excl[tid + 256 - off] : 0;
        __syncthreads();
        excl[tid] += a0;
        excl[tid + 256] += a1;
        __syncthreads();
    }
    // exclusive prefix + per-bucket global reservation
    int inc0 = excl[tid], inc1 = excl[tid + 256];
    int h0 = hist[tid],  h1 = hist[tid + 256];
    __syncthreads();
    int e0 = inc0 - h0, e1 = inc1 - h1;
    excl[tid] = e0; excl[tid + 256] = e1;
    lcur[tid] = e0; lcur[tid + 256] = e1;
    if (h0 > 0) gbase[tid]       = atomicAdd(&gbcur[tid * 16], h0);
    if (h1 > 0) gbase[tid + 256] = atomicAdd(&gbcur[(tid + 256) * 16], h1);
    __syncthreads();

    // LDS counting sort: place each edge into its bucket run
    for (int i = tid; i < nval; i += 256) {
        int b = sh_b[i];
        int pos = atomicAdd(&lcur[b], 1);
        sh_sorted[pos] = sh_p[i];
        sh_bs[pos] = (unsigned short)b;
    }
    __syncthreads();

    // stream out: consecutive sorted slots -> consecutive global addresses
    for (int i = tid; i < nval; i += 256) {
        int b = sh_bs[i];
        int gpos = gbase[b] + (i - excl[b]);
        if (gpos < CAP2)
            buf[(size_t)b * CAP2 + gpos] = (int)sh_sorted[i];
    }
}

// Exclusive prefix over bucket totals -> bucket_base; set rowptr[NN]=EE.
__global__ void bucket_scan_kernel(const int* __restrict__ gbcur, int* __restrict__ bucket_base,
                                   int* __restrict__ rowptr) {
    __shared__ int s[512];
    int tid = threadIdx.x;
    int v = 0;
    if (tid < NBKT) {
        int c = gbcur[tid * 16];
        v = (c < CAP2) ? c : CAP2;
    }
    s[tid] = v;
    __syncthreads();
    for (int off = 1; off < 512; off <<= 1) {
        int t = (tid >= off) ? s[tid - off] : 0;
        __syncthreads();
        s[tid] += t;
        __syncthreads();
    }
    if (tid < NBKT) bucket_base[tid] = s[tid] - v;
    if (tid == 0) rowptr[NN] = EE;
}

__global__ void dinv_kernel(const int* __restrict__ indeg_rep, float* __restrict__ dinv) {
    int i = blockIdx.x * blockDim.x + threadIdx.x;
    if (i < NN) {
        int ind = 1;
        #pragma unroll
        for (int r = 0; r < 8; ++r) ind += indeg_rep[r * NPAD + i];
        dinv[i] = rsqrtf((float)ind);
    }
}

// Cast fp32 inputs to pre-scaled f16: zx[i] = dinv[i]*x0[i], zy[i] = dinv[i]*y0[i].
__global__ void cast_kernel(const float4* __restrict__ x0, const float4* __restrict__ y0,
                            const float* __restrict__ dinv, uint4* __restrict__ zx,
                            uint4* __restrict__ zy) {
    int t = blockIdx.x * blockDim.x + threadIdx.x;
    if (t < NN * 16) {
        int node = t >> 4, c = t & 15;
        float di = dinv[node];
        float4 a = x0[(size_t)node * 32 + c * 2];
        float4 b = x0[(size_t)node * 32 + c * 2 + 1];
        uint4 o;
        o.x = packh(di * a.x, di * a.y); o.y = packh(di * a.z, di * a.w);
        o.z = packh(di * b.x, di * b.y); o.w = packh(di * b.z, di * b.w);
        zx[(size_t)node * 16 + c] = o;
    } else if (t < NN * 20) {
        int u = t - NN * 16;
        int node = u >> 2, c = u & 3;
        float di = dinv[node];
        float4 a = y0[(size_t)node * 8 + c * 2];
        float4 b = y0[(size_t)node * 8 + c * 2 + 1];
        uint4 o;
        o.x = packh(di * a.x, di * a.y); o.y = packh(di * a.z, di * a.w);
        o.z = packh(di * b.x, di * b.y); o.w = packh(di * b.z, di * b.w);
        zy[(size_t)node * 4 + c] = o;
    }
}

// One WG per bucket: stage run + histogram -> scan -> rowptr + contiguous dst slice.
__global__ __launch_bounds__(256) void passB_kernel(const int* __restrict__ gbcur,
                                                    const int* __restrict__ buf,
                                                    const int* __restrict__ bucket_base,
                                                    int* __restrict__ rowptr,
                                                    int* __restrict__ dst_sorted) {
    int b = blockIdx.x;
    int tid = threadIdx.x;
    __shared__ int edges[CAP2];      // 20 KB
    __shared__ int hist[256];
    __shared__ int sc[256];
    __shared__ int base_s, tot_s;

    if (tid == 0) {
        int c = gbcur[b * 16];
        tot_s = (c < CAP2) ? c : CAP2;
        base_s = bucket_base[b];
    }
    hist[tid] = 0;
    __syncthreads();
    int total = tot_s;
    const int* src = buf + (size_t)b * CAP2;
    for (int i = tid; i < total; i += 256) {
        int p = src[i];
        edges[i] = p;
        atomicAdd(&hist[p >> 17], 1);
    }
    __syncthreads();
    int hv = hist[tid];
    sc[tid] = hv;
    __syncthreads();
    for (int o = 1; o < 256; o <<= 1) {
        int t = (tid >= o) ? sc[tid - o] : 0;
        __syncthreads();
        sc[tid] += t;
        __syncthreads();
    }
    int excl = sc[tid] - hv;
    int node = (b << 8) + tid;
    if (node < NN) rowptr[node] = base_s + excl;
    hist[tid] = excl;
    __syncthreads();
    for (int i = tid; i < total; i += 256) {
        int p = edges[i];
        int pos = atomicAdd(&hist[p >> 17], 1);
        dst_sorted[base_s + pos] = p & 0x1ffff;
    }
}

// ---------- fused per-hop kernel (R9 structure, f16 z) ----------
// Iterates stored pre-scaled: z = dinv*u (f16). Per row:
//   u'_row = 0.9*di*sum_e z[d_e] + (0.9*di + 0.1/di)*z_row ; store z' = di*u' (or u' fp32).
// Merged 16-edge-batch loop: 5 independent gathers per iteration (MLP=5).
template <bool OUTH>
__global__ __launch_bounds__(256) void hop_kernel(const int* __restrict__ rowptr,
                                                  const int* __restrict__ dst_sorted,
                                                  const float* __restrict__ dinv,
                                                  const uint4* __restrict__ zx,
                                                  const uint4* __restrict__ zy,
                                                  void* __restrict__ nx,
                                                  void* __restrict__ ny) {
    int t = blockIdx.x * blockDim.x + threadIdx.x;
    int row = t >> 6, lane = t & 63;
    if (row >= NN) return;
    int beg = rowptr[row], end = rowptr[row + 1];
    float di = dinv[row];

    int g = lane >> 4, sub = lane & 15;    // x: 4 edge-groups x 16 lanes
    int gy = lane >> 2, sy = lane & 3;     // y: 16 edge-groups x 4 lanes

    float ax[8] = {0.f, 0.f, 0.f, 0.f, 0.f, 0.f, 0.f, 0.f};
    float ay[8] = {0.f, 0.f, 0.f, 0.f, 0.f, 0.f, 0.f, 0.f};

    int last = (end > beg) ? end - 1 : beg;
    for (int e0 = beg; e0 < end; e0 += 16) {
        int ex0 = e0 + g, ex1 = e0 + 4 + g, ex2 = e0 + 8 + g, ex3 = e0 + 12 + g;
        int ey = e0 + gy;
        // clamped indices -> always-valid addresses; contribution masked by 0/1
        int d0 = dst_sorted[min(ex0, last)];
        int d1 = dst_sorted[min(ex1, last)];
        int d2 = dst_sorted[min(ex2, last)];
        int d3 = dst_sorted[min(ex3, last)];
        int dy = dst_sorted[min(ey, last)];
        // 5 independent 16B gathers, all in flight together
        uint4 w0 = zx[(size_t)d0 * 16 + sub];
        uint4 w1 = zx[(size_t)d1 * 16 + sub];
        uint4 w2 = zx[(size_t)d2 * 16 + sub];
        uint4 w3 = zx[(size_t)d3 * 16 + sub];
        uint4 wy = zy[(size_t)dy * 4 + sy];
        float m0 = (ex0 <= last) ? 1.f : 0.f;
        float m1 = (ex1 <= last) ? 1.f : 0.f;
        float m2 = (ex2 <= last) ? 1.f : 0.f;
        float m3 = (ex3 <= last) ? 1.f : 0.f;
        float my = (ey  <= last) ? 1.f : 0.f;

        acc8(ax, w0, m0);
        acc8(ax, w1, m1);
        acc8(ax, w2, m2);
        acc8(ax, w3, m3);
        acc8(ay, wy, my);
    }

    #pragma unroll
    for (int m = 16; m <= 32; m <<= 1) {
        #pragma unroll
        for (int i = 0; i < 8; ++i) ax[i] += __shfl_xor(ax[i], m);
    }
    #pragma unroll
    for (int m = 4; m <= 32; m <<= 1) {
        #pragma unroll
        for (int i = 0; i < 8; ++i) ay[i] += __shfl_xor(ay[i], m);
    }

    float sg = 0.9f * di;
    float sl = 0.9f * di + 0.1f / di;   // coefficient on z_row giving the u-space self term

    if (g == 0) {   // lanes 0..15 write x
        uint4 wz = zx[(size_t)row * 16 + sub];
        float c[8];
        unp8(c, wz);
        float r[8];
        #pragma unroll
        for (int i = 0; i < 8; ++i) r[i] = sg * ax[i] + sl * c[i];   // u'
        if constexpr (OUTH) {
            uint4 o;
            o.x = packh(di * r[0], di * r[1]); o.y = packh(di * r[2], di * r[3]);
            o.z = packh(di * r[4], di * r[5]); o.w = packh(di * r[6], di * r[7]);
            ((uint4*)nx)[(size_t)row * 16 + sub] = o;
        } else {
            float4 a, b;
            a.x = r[0]; a.y = r[1]; a.z = r[2]; a.w = r[3];
            b.x = r[4]; b.y = r[5]; b.z = r[6]; b.w = r[7];
            ((float4*)nx)[(size_t)row * 32 + sub * 2]     = a;
            ((float4*)nx)[(size_t)row * 32 + sub * 2 + 1] = b;
        }
    }
    if (gy == 0) {  // lanes 0..3 write y
        uint4 wz = zy[(size_t)row * 4 + sy];
        float c[8];
        unp8(c, wz);
        float r[8];
        #pragma unroll
        for (int i = 0; i < 8; ++i) r[i] = sg * ay[i] + sl * c[i];
        if constexpr (OUTH) {
            uint4 o;
            o.x = packh(di * r[0], di * r[1]); o.y = packh(di * r[2], di * r[3]);
            o.z = packh(di * r[4], di * r[5]); o.w = packh(di * r[6], di * r[7]);
            ((uint4*)ny)[(size_t)row * 4 + sy] = o;
        } else {
            float4 a, b;
            a.x = r[0]; a.y = r[1]; a.z = r[2]; a.w = r[3];
            b.x = r[4]; b.y = r[5]; b.z = r[6]; b.w = r[7];
            ((float4*)ny)[(size_t)row * 8 + sy * 2]     = a;
            ((float4*)ny)[(size_t)row * 8 + sy * 2 + 1] = b;
        }
    }
}

extern "C" void kernel_launch(void* const* d_in, const int* in_sizes, int n_in,
                              void* d_out, int out_size, void* d_ws, size_t ws_size,
                              hipStream_t stream) {
    const float* x0  = (const float*)d_in[0];
    const float* y0  = (const float*)d_in[1];
    const void*  raw = d_in[2];

    float* out_x = (float*)d_out;
    float* out_y = out_x + (size_t)NN * 128;

    // ws layout (4-byte words):
    // flag[16] | indeg_rep[8*NPAD] | gbcur[512*16] | bucket_base[512] | rowptr[100112]
    // | dinv[NPAD] | buf[NBKT*CAP2] | dst_sorted[EE] | zxA[N*64] | zxB[N*64]
    // | zyA[N*16] | zyB[N*16]   ~= 78 MB
    int*   flag        = (int*)d_ws;
    int*   indeg_rep   = flag + 16;
    int*   gbcur       = indeg_rep + 8 * NPAD;
    int*   bucket_base = gbcur + 512 * 16;
    int*   rowptr      = bucket_base + 512;
    float* dinv        = (float*)(rowptr + 100112);
    int*   buf         = (int*)(dinv + NPAD);
    int*   dst_sorted  = buf + (size_t)NBKT * CAP2;
    uint4* zxA         = (uint4*)(dst_sorted + EE);
    uint4* zxB         = zxA + (size_t)NN * 16;
    uint4* zyA         = (uint4*)(zxB + (size_t)NN * 16);
    uint4* zyB         = zyA + (size_t)NN * 4;

    const int B = 256;
    const int GW = (NN * 64 + B - 1) / B;   // one wave per row
    const int ZTOT = 8 * NPAD + 512 * 16;

    zero_kernel<<<(ZTOT + B - 1) / B, B, 0, stream>>>(indeg_rep, ZTOT, (const int*)raw, flag);
    passA_kernel<<<(EE + CHUNK - 1) / CHUNK, 256, 0, stream>>>(raw, flag, indeg_rep, gbcur, buf);
    bucket_scan_kernel<<<1, 512, 0, stream>>>(gbcur, bucket_base, rowptr);
    dinv_kernel<<<(NN + B - 1) / B, B, 0, stream>>>(indeg_rep, dinv);
    cast_kernel<<<(NN * 20 + B - 1) / B, B, 0, stream>>>(
        (const float4*)x0, (const float4*)y0, dinv, zxA, zyA);
    passB_kernel<<<NBKT, 256, 0, stream>>>(gbcur, buf, bucket_base, rowptr, dst_sorted);

    // hops 1-3: f16 z -> f16 z ; hop 4: f16 z -> fp32 u (d_out)
    hop_kernel<true><<<GW, B, 0, stream>>>(rowptr, dst_sorted, dinv, zxA, zyA, zxB, zyB);
    hop_kernel<true><<<GW, B, 0, stream>>>(rowptr, dst_sorted, dinv, zxB, zyB, zxA, zyA);
    hop_kernel<true><<<GW, B, 0, stream>>>(rowptr, dst_sorted, dinv, zxA, zyA, zxB, zyB);
    hop_kernel<false><<<GW, B, 0, stream>>>(rowptr, dst_sorted, dinv, zxB, zyB, out_x, out_y);
}